// Round 21
// baseline (367.674 us; speedup 1.0000x reference)
//
#include <hip/hip_runtime.h>
#include <hip/hip_bf16.h>
#include <cstddef>

#define B_   16
#define N_   1024
#define H_   2
#define D_   128
#define A_   256
#define FFN_ 1024
#define M_   (B_ * N_)   // 16384 rows
#define EPS_ 1e-5f
#define SPLIT 2
#define KT   32                    // keys per tile
#define TPC  (N_ / SPLIT / KT)     // tiles per chunk = 16
#define QKV_E ((size_t)B_ * H_ * N_ * D_)

typedef short  short8  __attribute__((ext_vector_type(8)));
typedef float  f32x16  __attribute__((ext_vector_type(16)));
typedef unsigned int uint;
typedef unsigned short ushort;

#define MFMA32(a, b, c) __builtin_amdgcn_mfma_f32_32x32x16_bf16(a, b, c, 0, 0, 0)

__device__ __forceinline__ uint f2b1(float x) {
    uint u = __float_as_uint(x);
    return (u + 0x7fffu + ((u >> 16) & 1u)) >> 16;
}
__device__ __forceinline__ uint f2b2(float lo, float hi) {
    return f2b1(lo) | (f2b1(hi) << 16);
}
__device__ __forceinline__ float b2f(ushort u) {
    return __uint_as_float(((uint)u) << 16);
}

// ---------------------------------------------------------------------------
// fp32 -> bf16 bulk convert (8 elems/thread)
// ---------------------------------------------------------------------------
__global__ __launch_bounds__(256) void f32_to_bf16_kernel(
    const float* __restrict__ in, ushort* __restrict__ out)
{
    const size_t i = ((size_t)blockIdx.x * 256 + threadIdx.x) * 8;
    float4 a = *(const float4*)(in + i);
    float4 b = *(const float4*)(in + i + 4);
    uint4 w = { f2b2(a.x, a.y), f2b2(a.z, a.w), f2b2(b.x, b.y), f2b2(b.z, b.w) };
    *(uint4*)(out + i) = w;
}

// ---------------------------------------------------------------------------
// Unified weight prep (one launch): z 0-8 QKV(layer,sec), 9-11 W1, 12-14 W2,
// 15 Wc. W[K][N] fp32 -> Wt[N][K] bf16. W2 swaps x/y so grid (32,8,16) fits.
// ---------------------------------------------------------------------------
__global__ __launch_bounds__(256) void prep_kernel(
    const float* __restrict__ Wq, const float* __restrict__ Wk,
    const float* __restrict__ Wv, const float* __restrict__ W1,
    const float* __restrict__ W2, const float* __restrict__ Wc,
    ushort* __restrict__ wqkv_t, ushort* __restrict__ w1_t,
    ushort* __restrict__ w2_t, ushort* __restrict__ wc_t)
{
    const int z = blockIdx.z;
    const float* W; ushort* out; int K, N, n0, k0;
    if (z < 9) {
        const int layer = z / 3, sec = z % 3;
        W = (sec == 0 ? Wq : sec == 1 ? Wk : Wv) + (size_t)layer * A_ * A_;
        out = wqkv_t + (size_t)layer * 3 * A_ * A_ + (size_t)sec * A_ * A_;
        K = A_; N = A_;
        n0 = blockIdx.x * 32; k0 = blockIdx.y * 32;
    } else if (z < 12) {
        const int layer = z - 9;
        W = W1 + (size_t)layer * A_ * FFN_; out = w1_t + (size_t)layer * A_ * FFN_;
        K = A_; N = FFN_;
        n0 = blockIdx.x * 32; k0 = blockIdx.y * 32;
    } else if (z < 15) {
        const int layer = z - 12;
        W = W2 + (size_t)layer * FFN_ * A_; out = w2_t + (size_t)layer * FFN_ * A_;
        K = FFN_; N = A_;
        k0 = blockIdx.x * 32; n0 = blockIdx.y * 32;   // swapped roles
    } else {
        W = Wc; out = wc_t; K = A_; N = A_;
        n0 = blockIdx.x * 32; k0 = blockIdx.y * 32;
    }
    if (n0 >= N || k0 >= K) return;

    __shared__ float tile[32][33];
    const int tc = threadIdx.x & 31, tr = threadIdx.x >> 5;
#pragma unroll
    for (int it = 0; it < 4; ++it) {
        int r = it * 8 + tr;
        tile[r][tc] = W[(size_t)(k0 + r) * N + n0 + tc];
    }
    __syncthreads();
#pragma unroll
    for (int it = 0; it < 4; ++it) {
        int r = it * 8 + tr;
        out[(size_t)(n0 + r) * K + k0 + tc] = (ushort)f2b1(tile[tc][r]);
    }
}

// ---------------------------------------------------------------------------
// MFMA GEMM, templated row-tile: MR=2 -> BM=128, MR=1 -> BM=64 (skinny-N/K).
// modes: 1 = relu fp32   2 = relu bf16   5 = fused QKV fragment-major
//        6 = relu + fused pool (atomicAdd)
//        8 = relu bf16 with FUSED split-KV combine A-staging:
//            Asrc = po partials [z][bh][n][d] bf16; biasK = pm, biasV = pl.
// ---------------------------------------------------------------------------
template <int MR>
__global__ __launch_bounds__(256) void gemm_mfma(
    const ushort* __restrict__ Asrc, const ushort* __restrict__ Wt,
    const float* __restrict__ bias, const float* __restrict__ biasK,
    const float* __restrict__ biasV, void* __restrict__ outp,
    int Kloop, int lda, int ldc, int mode)
{
    constexpr int BM = MR * 64;
    __shared__ ushort sA[BM * 72];
    __shared__ ushort sB[128 * 72];

    const int tid = threadIdx.x;
    const int wid = tid >> 6, lane = tid & 63;
    const int c = lane & 31, g = lane >> 5;
    const int wr = wid >> 1, wc = wid & 1;
    const int m0 = blockIdx.x * BM;
    const int n0 = blockIdx.y * 128;

    f32x16 acc[MR][2] = {};

    for (int k0 = 0; k0 < Kloop; k0 += 64) {
        __syncthreads();
        if (mode == 8) {
            // fused split-KV combine: stage A = combine(po[z=0], po[z=1])
#pragma unroll
            for (int it = 0; it < BM / 32; ++it) {
                int idx = it * 256 + tid, r = idx >> 3, cc = (idx & 7) * 8;
                const int row = m0 + r;
                const int bb2 = row >> 10, nn = row & (N_ - 1);
                const int col = k0 + cc;
                const int hh = col >> 7, d0 = col & (D_ - 1);
                const int pr = (((bb2 << 1) | hh) << 10) + nn;   // bh*N + n
                const float ms0 = biasK[pr], ms1 = biasK[32 * N_ + pr];
                const float Mx = fmaxf(ms0, ms1);
                const float w0 = exp2f(ms0 - Mx), w1 = exp2f(ms1 - Mx);
                const float invL = 1.f / (biasV[pr] * w0 + biasV[32 * N_ + pr] * w1);
                const float f0 = w0 * invL, f1 = w1 * invL;
                uint4 pa = *(const uint4*)(Asrc + (size_t)pr * D_ + d0);
                uint4 pb = *(const uint4*)(Asrc + QKV_E + (size_t)pr * D_ + d0);
                const ushort* pua = (const ushort*)&pa;
                const ushort* pub = (const ushort*)&pb;
                uint4 wv;
                uint* wp = (uint*)&wv;
#pragma unroll
                for (int j = 0; j < 4; ++j) {
                    float e0 = b2f(pua[2 * j])     * f0 + b2f(pub[2 * j])     * f1;
                    float e1 = b2f(pua[2 * j + 1]) * f0 + b2f(pub[2 * j + 1]) * f1;
                    wp[j] = f2b2(e0, e1);
                }
                *(uint4*)&sA[r * 72 + cc] = wv;
            }
        } else {
#pragma unroll
            for (int it = 0; it < BM / 32; ++it) {
                int idx = it * 256 + tid, r = idx >> 3, cc = (idx & 7) * 8;
                *(uint4*)&sA[r * 72 + cc] =
                    *(const uint4*)(Asrc + (size_t)(m0 + r) * lda + k0 + cc);
            }
        }
#pragma unroll
        for (int it = 0; it < 4; ++it) {
            int idx = it * 256 + tid, r = idx >> 3, cc = (idx & 7) * 8;
            *(uint4*)&sB[r * 72 + cc] =
                *(const uint4*)(Wt + (size_t)(n0 + r) * lda + k0 + cc);
        }
        __syncthreads();
#pragma unroll
        for (int ks = 0; ks < 4; ++ks) {
            const int ko = ks * 16 + 8 * g;
            short8 b0 = *(const short8*)&sB[(wc * 64 + c) * 72 + ko];
            short8 b1 = *(const short8*)&sB[(wc * 64 + 32 + c) * 72 + ko];
#pragma unroll
            for (int mr = 0; mr < MR; ++mr) {
                short8 a = *(const short8*)&sA[((wr * MR + mr) * 32 + c) * 72 + ko];
                acc[mr][0] = MFMA32(a, b0, acc[mr][0]);
                acc[mr][1] = MFMA32(a, b1, acc[mr][1]);
            }
        }
    }

    const int sec = n0 >> 8;  // for mode 5 (block-uniform)
    const float* bp = bias;
    int nw = n0;
    if (mode == 5) {
        bp = (sec == 0 ? bias : sec == 1 ? biasK : biasV);
        nw = n0 & 255;
    }
    const float bz[2] = { bp[nw + wc * 64 + c], bp[nw + wc * 64 + 32 + c] };

    float colsum[2] = { 0.f, 0.f };

#pragma unroll
    for (int mr = 0; mr < MR; ++mr) {
#pragma unroll
        for (int ct = 0; ct < 2; ++ct) {
            const int colbase = n0 + wc * 64 + ct * 32 + c;
#pragma unroll
            for (int rg = 0; rg < 4; ++rg) {
                const int row = m0 + (wr * MR + mr) * 32 + 8 * rg + 4 * g;
                float v0 = acc[mr][ct][4 * rg + 0] + bz[ct];
                float v1 = acc[mr][ct][4 * rg + 1] + bz[ct];
                float v2 = acc[mr][ct][4 * rg + 2] + bz[ct];
                float v3 = acc[mr][ct][4 * rg + 3] + bz[ct];
                if (mode == 1 || mode == 2 || mode == 6 || mode == 8) {
                    v0 = fmaxf(v0, 0.f); v1 = fmaxf(v1, 0.f);
                    v2 = fmaxf(v2, 0.f); v3 = fmaxf(v3, 0.f);
                }
                if (mode == 1) {
                    float* o = (float*)outp;
                    o[(size_t)(row + 0) * ldc + colbase] = v0;
                    o[(size_t)(row + 1) * ldc + colbase] = v1;
                    o[(size_t)(row + 2) * ldc + colbase] = v2;
                    o[(size_t)(row + 3) * ldc + colbase] = v3;
                } else if (mode == 2 || mode == 8) {
                    ushort* o = (ushort*)outp;
                    o[(size_t)(row + 0) * ldc + colbase] = (ushort)f2b1(v0);
                    o[(size_t)(row + 1) * ldc + colbase] = (ushort)f2b1(v1);
                    o[(size_t)(row + 2) * ldc + colbase] = (ushort)f2b1(v2);
                    o[(size_t)(row + 3) * ldc + colbase] = (ushort)f2b1(v3);
                } else if (mode == 6) {
                    colsum[ct] += v0 + v1 + v2 + v3;
                } else {  // mode 5, fragment-major
                    const int cw = colbase & 255;
                    const int hh = cw >> 7, dd = cw & (D_ - 1);
                    if (sec < 2) {
                        ushort* o = (ushort*)outp + (size_t)sec * QKV_E;
#pragma unroll
                        for (int r2 = 0; r2 < 4; ++r2) {
                            int rw = row + r2;
                            int bb = rw >> 10, np = rw & (N_ - 1);
                            float vv = (r2 == 0 ? v0 : r2 == 1 ? v1 : r2 == 2 ? v2 : v3);
                            size_t off = (((size_t)(bb * H_ + hh) * 32 + (np >> 5)) * 16
                                          + (dd >> 3)) * 256
                                         + (np & 31) * 8 + (dd & 7);
                            o[off] = (ushort)f2b1(vv);
                        }
                    } else {
                        ushort* o = (ushort*)outp + 2 * QKV_E;
                        const int bb = row >> 10, np = row & (N_ - 1);
                        size_t off = ((((size_t)(bb * H_ + hh) * 32 + (np >> 5)) * 4
                                       + (dd >> 5)) * 4 + ((np & 31) >> 3)) * 256
                                     + (dd & 31) * 8 + (np & 7);
                        uint2 w = { f2b2(v0, v1), f2b2(v2, v3) };
                        *(uint2*)(o + off) = w;
                    }
                }
            }
        }
    }

    if (mode == 6) {
        float* part = (float*)outp;
        const int b = m0 >> 10;   // BM=64 divides 1024
#pragma unroll
        for (int ct = 0; ct < 2; ++ct) {
            float cs = colsum[ct] + __shfl_xor(colsum[ct], 32, 64);
            if (g == 0)
                atomicAdd(&part[(size_t)b * A_ + n0 + wc * 64 + ct * 32 + c], cs);
        }
    }
}

// ---------------------------------------------------------------------------
// Flash attention, barrier-free, fragment-major operands (R14/R18-proven).
// SPLIT=2: measured optimum. 1024 blocks keep ~2 resident waves/SIMD.
// ---------------------------------------------------------------------------
#define OPITCH 132   // epilogue overlay pitch (66 words: bank-stride 2, free)

__global__ __launch_bounds__(128, 2) void attn_kernel(
    const ushort* __restrict__ qg, const ushort* __restrict__ kg,
    const ushort* __restrict__ vtg, ushort* __restrict__ po,
    float* __restrict__ pm, float* __restrict__ pl)
{
    __shared__ ushort sO[64 * OPITCH];   // 16896 B, epilogue only

    const int tid = threadIdx.x;
    const int w = tid >> 6, lane = tid & 63;
    const int c = lane & 31, g = lane >> 5;

    const int flat = blockIdx.x;          // 0..1023
    const int xcd  = flat & 7;
    const int ii   = flat >> 3;           // 0..127
    const int pair = xcd * 8 + (ii & 7);  // 0..63 = (z,bh)
    const int qt   = ii >> 3;             // 0..15
    const int bh   = pair & 31;
    const int z    = pair >> 5;           // 0..1

    const int q0 = qt * 64 + w * 32;
    const float scale2 = 0.08838834764831845f * 1.44269504f;  // /sqrt(128)*log2e
    const float THR = 11.5f;
    const int lo8 = c * 8;

    short8 qf[8];
    const ushort* qt_ = qg + ((size_t)bh * 32 + (q0 >> 5)) * 4096;
#pragma unroll
    for (int ks = 0; ks < 8; ++ks)
        qf[ks] = *(const short8*)(qt_ + (2 * ks + g) * 256 + lo8);

    f32x16 oacc[4] = {};
    float m = -1e30f, l = 0.f;

    // K prefetch for tile 0 (named regs; rule #20: no arrays)
    const size_t chunk0 = ((size_t)bh * 32 + z * TPC) * 4096;
    const ushort* kb0 = kg + chunk0 + g * 256 + lo8;
    short8 kf0 = *(const short8*)(kb0 + 0 * 512);
    short8 kf1 = *(const short8*)(kb0 + 1 * 512);
    short8 kf2 = *(const short8*)(kb0 + 2 * 512);
    short8 kf3 = *(const short8*)(kb0 + 3 * 512);
    short8 kf4 = *(const short8*)(kb0 + 4 * 512);
    short8 kf5 = *(const short8*)(kb0 + 5 * 512);
    short8 kf6 = *(const short8*)(kb0 + 6 * 512);
    short8 kf7 = *(const short8*)(kb0 + 7 * 512);

    for (int t = 0; t < TPC; ++t) {
        const size_t tb = chunk0 + (size_t)t * 4096;

        // ---- issue V(t) loads first: QK's MFMA chain below covers them ----
        const ushort* vb = vtg + tb + g * 256 + lo8;
        short8 vfA0 = *(const short8*)(vb + 0 * 1024);
        short8 vfA1 = *(const short8*)(vb + 1 * 1024);
        short8 vfA2 = *(const short8*)(vb + 2 * 1024);
        short8 vfA3 = *(const short8*)(vb + 3 * 1024);
        short8 vfB0 = *(const short8*)(vb + 0 * 1024 + 512);
        short8 vfB1 = *(const short8*)(vb + 1 * 1024 + 512);
        short8 vfB2 = *(const short8*)(vb + 2 * 1024 + 512);
        short8 vfB3 = *(const short8*)(vb + 3 * 1024 + 512);
        __builtin_amdgcn_sched_barrier(0);

        // ---- S^T = K · Q^T  (K already in registers) ----
        f32x16 sacc = {};
        __builtin_amdgcn_s_setprio(1);
        sacc = MFMA32(kf0, qf[0], sacc);
        sacc = MFMA32(kf1, qf[1], sacc);
        sacc = MFMA32(kf2, qf[2], sacc);
        sacc = MFMA32(kf3, qf[3], sacc);
        sacc = MFMA32(kf4, qf[4], sacc);
        sacc = MFMA32(kf5, qf[5], sacc);
        sacc = MFMA32(kf6, qf[6], sacc);
        sacc = MFMA32(kf7, qf[7], sacc);
        __builtin_amdgcn_s_setprio(0);

        // ---- prefetch K(t+1): lands during softmax+PV below ----
        if (t + 1 < TPC) {
            const ushort* kb2 = kg + tb + 4096 + g * 256 + lo8;
            kf0 = *(const short8*)(kb2 + 0 * 512);
            kf1 = *(const short8*)(kb2 + 1 * 512);
            kf2 = *(const short8*)(kb2 + 2 * 512);
            kf3 = *(const short8*)(kb2 + 3 * 512);
            kf4 = *(const short8*)(kb2 + 4 * 512);
            kf5 = *(const short8*)(kb2 + 5 * 512);
            kf6 = *(const short8*)(kb2 + 6 * 512);
            kf7 = *(const short8*)(kb2 + 7 * 512);
        }
        __builtin_amdgcn_sched_barrier(0);

        // ---- online softmax (exp2 domain, defer-max) ----
        float p[16];
        float tmax = -1e30f;
#pragma unroll
        for (int r = 0; r < 16; ++r) {
            float s = sacc[r] * scale2;
            p[r] = s;
            tmax = fmaxf(tmax, s);
        }
        tmax = fmaxf(tmax, __shfl_xor(tmax, 32, 64));
        if (!__all(tmax - m <= THR)) {
            const float mnew = fmaxf(m, tmax);
            const float corr = exp2f(m - mnew);
#pragma unroll
            for (int dt = 0; dt < 4; ++dt)
#pragma unroll
                for (int r = 0; r < 16; ++r) oacc[dt][r] *= corr;
            l *= corr;
            m = mnew;
        }
        float tsum = 0.f;
#pragma unroll
        for (int r = 0; r < 16; ++r) {
            p[r] = exp2f(p[r] - m);
            tsum += p[r];
        }
        tsum += __shfl_xor(tsum, 32, 64);
        l += tsum;

        uint pk[8];
#pragma unroll
        for (int pp = 0; pp < 8; ++pp)
            pk[pp] = f2b2(p[2 * pp], p[2 * pp + 1]);

        uint v0 = g ? pk[0] : pk[2];
        uint v1 = g ? pk[1] : pk[3];
        uint v2 = g ? pk[4] : pk[6];
        uint v3 = g ? pk[5] : pk[7];
        uint r0 = (uint)__shfl_xor((int)v0, 32, 64);
        uint r1 = (uint)__shfl_xor((int)v1, 32, 64);
        uint r2 = (uint)__shfl_xor((int)v2, 32, 64);
        uint r3 = (uint)__shfl_xor((int)v3, 32, 64);

        // ---- O^T += V^T · P^T  (V already in registers) ----
        __builtin_amdgcn_s_setprio(1);
#pragma unroll
        for (int kb = 0; kb < 2; ++kb) {
            union { uint u[4]; short8 s; } pf;
            if (kb == 0) {
                pf.u[0] = g ? r0 : pk[0];
                pf.u[1] = g ? r1 : pk[1];
                pf.u[2] = g ? pk[2] : r0;
                pf.u[3] = g ? pk[3] : r1;
            } else {
                pf.u[0] = g ? r2 : pk[4];
                pf.u[1] = g ? r3 : pk[5];
                pf.u[2] = g ? pk[6] : r2;
                pf.u[3] = g ? pk[7] : r3;
            }
            oacc[0] = MFMA32(kb ? vfB0 : vfA0, pf.s, oacc[0]);
            oacc[1] = MFMA32(kb ? vfB1 : vfA1, pf.s, oacc[1]);
            oacc[2] = MFMA32(kb ? vfB2 : vfA2, pf.s, oacc[2]);
            oacc[3] = MFMA32(kb ? vfB3 : vfA3, pf.s, oacc[3]);
        }
        __builtin_amdgcn_s_setprio(0);
    }

    if (lane < 32) {
        pm[(size_t)(z * 32 + bh) * N_ + q0 + c] = m;
        pl[(size_t)(z * 32 + bh) * N_ + q0 + c] = l;
    }
    {
        const int qrl = w * 32 + c;
#pragma unroll
        for (int dt = 0; dt < 4; ++dt)
#pragma unroll
            for (int rg = 0; rg < 4; ++rg) {
                int d = dt * 32 + 8 * rg + 4 * g;
                uint2 pv = { f2b2(oacc[dt][4 * rg + 0], oacc[dt][4 * rg + 1]),
                             f2b2(oacc[dt][4 * rg + 2], oacc[dt][4 * rg + 3]) };
                *(uint2*)&sO[qrl * OPITCH + d] = pv;
            }
    }
    __syncthreads();
    {
        const size_t pbase = ((size_t)(z * 32 + bh) * N_ + qt * 64) * D_;
#pragma unroll
        for (int it = 0; it < 16; ++it) {
            int idx = it * 128 + tid;
            int r = idx >> 5, dgr = (idx & 31) * 4;
            uint2 v = *(const uint2*)&sO[r * OPITCH + dgr];
            *(uint2*)(po + pbase + (size_t)r * D_ + dgr) = v;
        }
    }
}

// ---------------------------------------------------------------------------
// add+LN: stepb <- LN(roll + stepb)*g + b  (in place; roll = FFN2 relu bf16)
// wave-per-row (4 rows/block), shfl-only reduce, 4 elems/lane
// ---------------------------------------------------------------------------
__global__ __launch_bounds__(256) void add_ln_kernel(
    const ushort* __restrict__ roll, ushort* __restrict__ stepb,
    const float* __restrict__ g, const float* __restrict__ bta)
{
    const int row = blockIdx.x * 4 + (threadIdx.x >> 6);
    const int lane = threadIdx.x & 63, c4 = lane * 4;
    const size_t base = (size_t)row * A_ + c4;

    uint2 rb = *(const uint2*)(roll + base);
    uint2 pb = *(const uint2*)(stepb + base);
    float v0 = b2f((ushort)(rb.x & 0xffff)) + b2f((ushort)(pb.x & 0xffff));
    float v1 = b2f((ushort)(rb.x >> 16))    + b2f((ushort)(pb.x >> 16));
    float v2 = b2f((ushort)(rb.y & 0xffff)) + b2f((ushort)(pb.y & 0xffff));
    float v3 = b2f((ushort)(rb.y >> 16))    + b2f((ushort)(pb.y >> 16));

    float s  = v0 + v1 + v2 + v3;
    float s2 = v0 * v0 + v1 * v1 + v2 * v2 + v3 * v3;
#pragma unroll
    for (int o = 32; o > 0; o >>= 1) {
        s  += __shfl_xor(s, o, 64);
        s2 += __shfl_xor(s2, o, 64);
    }
    const float mu = s * (1.f / A_);
    const float rs = rsqrtf(s2 * (1.f / A_) - mu * mu + EPS_);

    float4 gv = *(const float4*)(g + c4);
    float4 bv = *(const float4*)(bta + c4);
    float y0 = (v0 - mu) * rs * gv.x + bv.x;
    float y1 = (v1 - mu) * rs * gv.y + bv.y;
    float y2 = (v2 - mu) * rs * gv.z + bv.z;
    float y3 = (v3 - mu) * rs * gv.w + bv.w;

    uint2 yb = { f2b2(y0, y1), f2b2(y2, y3) };
    *(uint2*)(stepb + base) = yb;
}

// ---------------------------------------------------------------------------
// Final: pooled = part/N -> relu(pooled @ We + be)
// ---------------------------------------------------------------------------
__global__ __launch_bounds__(256) void final_kernel(
    const float* __restrict__ part, const float* __restrict__ We,
    const float* __restrict__ be, float* __restrict__ out)
{
    __shared__ float sp[A_];
    const int b = blockIdx.x, tid = threadIdx.x;
    sp[tid] = part[(size_t)b * A_ + tid] * (1.0f / N_);
    __syncthreads();
    float acc = be[tid];
    for (int kk = 0; kk < A_; ++kk) acc += sp[kk] * We[(size_t)kk * A_ + tid];
    out[b * A_ + tid] = fmaxf(acc, 0.f);
}

// ---------------------------------------------------------------------------
extern "C" void kernel_launch(void* const* d_in, const int* in_sizes, int n_in,
                              void* d_out, int out_size, void* d_ws, size_t ws_size,
                              hipStream_t stream)
{
    const float* X    = (const float*)d_in[0];
    const float* Wq   = (const float*)d_in[1];
    const float* bq   = (const float*)d_in[2];
    const float* Wk   = (const float*)d_in[3];
    const float* bk   = (const float*)d_in[4];
    const float* Wv   = (const float*)d_in[5];
    const float* bv   = (const float*)d_in[6];
    const float* W1   = (const float*)d_in[7];
    const float* b1   = (const float*)d_in[8];
    const float* W2   = (const float*)d_in[9];
    const float* b2   = (const float*)d_in[10];
    const float* ln_g = (const float*)d_in[11];
    const float* ln_b = (const float*)d_in[12];
    const float* Wc   = (const float*)d_in[13];
    const float* bc   = (const float*)d_in[14];
    const float* We   = (const float*)d_in[15];
    const float* be   = (const float*)d_in[16];

    // ---- workspace layout (~72 MB, well under proven ~102 MB) ----
    // fbuf phases: [QKV writes q/k/vt] -> [attn reads] -> [FFN1 overwrites]
    char* base = (char*)d_ws;
    ushort* fbuf   = (ushort*)base;  base += (size_t)M_ * FFN_ * 2;      // 33.5MB
    ushort* po     = (ushort*)base;  base += (size_t)SPLIT * QKV_E * 2;  // 16.8MB
    ushort* rollb  = (ushort*)base;  base += (size_t)M_ * A_ * 2;        // FFN2 out
    ushort* stepb  = (ushort*)base;  base += (size_t)M_ * A_ * 2;        // residual
    ushort* wqkv_t = (ushort*)base;  base += (size_t)3 * 3 * A_ * A_ * 2;
    ushort* w1_t   = (ushort*)base;  base += (size_t)3 * A_ * FFN_ * 2;
    ushort* w2_t   = (ushort*)base;  base += (size_t)3 * FFN_ * A_ * 2;
    ushort* wc_t   = (ushort*)base;  base += (size_t)A_ * A_ * 2;
    float*  part   = (float*)base;   base += (size_t)B_ * A_ * 4;
    float*  pm     = (float*)base;   base += (size_t)SPLIT * B_ * H_ * N_ * 4;
    float*  pl     = (float*)base;   base += (size_t)SPLIT * B_ * H_ * N_ * 4;
    ushort* qb     = fbuf;
    ushort* kbuf   = fbuf + QKV_E;
    ushort* vtbuf  = fbuf + 2 * QKV_E;

    // ---- weight/input prep (2 launches) ----
    prep_kernel<<<dim3(32, 8, 16), 256, 0, stream>>>(
        Wq, Wk, Wv, W1, W2, Wc, wqkv_t, w1_t, w2_t, wc_t);
    f32_to_bf16_kernel<<<(M_ * A_) / (256 * 8), 256, 0, stream>>>(X, stepb);

    for (int i = 0; i < 3; ++i) {
        // fused QKV projection -> fragment-major q/k/vt in fbuf
        gemm_mfma<2><<<dim3(M_/128, 6), 256, 0, stream>>>(
            stepb, wqkv_t + (size_t)i * 3 * A_ * A_,
            bq + i * A_, bk + i * A_, bv + i * A_, qb, A_, A_, 0, 5);

        attn_kernel<<<16 * SPLIT * B_ * H_, 128, 0, stream>>>(
            qb, kbuf, vtbuf, po, pm, pl);

        // FFN1 mode 8: fused split-KV combine in A-staging (reads po/pm/pl),
        // writes into fbuf (q/k/vt dead after attn)
        gemm_mfma<2><<<dim3(M_/128, FFN_/128), 256, 0, stream>>>(
            po, w1_t + (size_t)i * A_ * FFN_, b1 + i * FFN_, pm, pl,
            fbuf, A_, A_, FFN_, 8);

        // FFN2 (non-split; R15 showed split-K neutral)
        gemm_mfma<1><<<dim3(M_/64, A_/128), 256, 0, stream>>>(
            fbuf, w2_t + (size_t)i * FFN_ * A_, b2 + i * A_, nullptr, nullptr,
            rollb, FFN_, FFN_, A_, 2);

        add_ln_kernel<<<M_/4, 256, 0, stream>>>(rollb, stepb, ln_g, ln_b);
    }

    // head: fused relu+pool via atomics into part (zeroed per call)
    hipMemsetAsync(part, 0, (size_t)B_ * A_ * 4, stream);
    gemm_mfma<1><<<dim3(M_/64, A_/128), 256, 0, stream>>>(
        stepb, wc_t, bc, nullptr, nullptr, part, A_, A_, 0, 6);
    final_kernel<<<B_, 256, 0, stream>>>(part, We, be, (float*)d_out);
}

// Round 22
// 335.884 us; speedup vs baseline: 1.0946x; 1.0946x over previous
//
#include <hip/hip_runtime.h>
#include <hip/hip_bf16.h>
#include <cstddef>

#define B_   16
#define N_   1024
#define H_   2
#define D_   128
#define A_   256
#define FFN_ 1024
#define M_   (B_ * N_)   // 16384 rows
#define EPS_ 1e-5f
#define SPLIT 2
#define KT   32                    // keys per tile
#define TPC  (N_ / SPLIT / KT)     // tiles per chunk = 16
#define QKV_E ((size_t)B_ * H_ * N_ * D_)

typedef short  short8  __attribute__((ext_vector_type(8)));
typedef float  f32x16  __attribute__((ext_vector_type(16)));
typedef unsigned int uint;
typedef unsigned short ushort;

#define MFMA32(a, b, c) __builtin_amdgcn_mfma_f32_32x32x16_bf16(a, b, c, 0, 0, 0)

__device__ __forceinline__ uint f2b1(float x) {
    uint u = __float_as_uint(x);
    return (u + 0x7fffu + ((u >> 16) & 1u)) >> 16;
}
__device__ __forceinline__ uint f2b2(float lo, float hi) {
    return f2b1(lo) | (f2b1(hi) << 16);
}
__device__ __forceinline__ float b2f(ushort u) {
    return __uint_as_float(((uint)u) << 16);
}

// ---------------------------------------------------------------------------
// fp32 -> bf16 bulk convert (8 elems/thread)
// ---------------------------------------------------------------------------
__global__ __launch_bounds__(256) void f32_to_bf16_kernel(
    const float* __restrict__ in, ushort* __restrict__ out)
{
    const size_t i = ((size_t)blockIdx.x * 256 + threadIdx.x) * 8;
    float4 a = *(const float4*)(in + i);
    float4 b = *(const float4*)(in + i + 4);
    uint4 w = { f2b2(a.x, a.y), f2b2(a.z, a.w), f2b2(b.x, b.y), f2b2(b.z, b.w) };
    *(uint4*)(out + i) = w;
}

// ---------------------------------------------------------------------------
// Unified weight prep (one launch): z 0-8 QKV(layer,sec), 9-11 W1, 12-14 W2,
// 15 Wc. W[K][N] fp32 -> Wt[N][K] bf16. W2 swaps x/y so grid (32,8,16) fits.
// ---------------------------------------------------------------------------
__global__ __launch_bounds__(256) void prep_kernel(
    const float* __restrict__ Wq, const float* __restrict__ Wk,
    const float* __restrict__ Wv, const float* __restrict__ W1,
    const float* __restrict__ W2, const float* __restrict__ Wc,
    ushort* __restrict__ wqkv_t, ushort* __restrict__ w1_t,
    ushort* __restrict__ w2_t, ushort* __restrict__ wc_t)
{
    const int z = blockIdx.z;
    const float* W; ushort* out; int K, N, n0, k0;
    if (z < 9) {
        const int layer = z / 3, sec = z % 3;
        W = (sec == 0 ? Wq : sec == 1 ? Wk : Wv) + (size_t)layer * A_ * A_;
        out = wqkv_t + (size_t)layer * 3 * A_ * A_ + (size_t)sec * A_ * A_;
        K = A_; N = A_;
        n0 = blockIdx.x * 32; k0 = blockIdx.y * 32;
    } else if (z < 12) {
        const int layer = z - 9;
        W = W1 + (size_t)layer * A_ * FFN_; out = w1_t + (size_t)layer * A_ * FFN_;
        K = A_; N = FFN_;
        n0 = blockIdx.x * 32; k0 = blockIdx.y * 32;
    } else if (z < 15) {
        const int layer = z - 12;
        W = W2 + (size_t)layer * FFN_ * A_; out = w2_t + (size_t)layer * FFN_ * A_;
        K = FFN_; N = A_;
        k0 = blockIdx.x * 32; n0 = blockIdx.y * 32;   // swapped roles
    } else {
        W = Wc; out = wc_t; K = A_; N = A_;
        n0 = blockIdx.x * 32; k0 = blockIdx.y * 32;
    }
    if (n0 >= N || k0 >= K) return;

    __shared__ float tile[32][33];
    const int tc = threadIdx.x & 31, tr = threadIdx.x >> 5;
#pragma unroll
    for (int it = 0; it < 4; ++it) {
        int r = it * 8 + tr;
        tile[r][tc] = W[(size_t)(k0 + r) * N + n0 + tc];
    }
    __syncthreads();
#pragma unroll
    for (int it = 0; it < 4; ++it) {
        int r = it * 8 + tr;
        out[(size_t)(n0 + r) * K + k0 + tc] = (ushort)f2b1(tile[tc][r]);
    }
}

// ---------------------------------------------------------------------------
// MFMA GEMM, templated row-tile: MR=2 -> BM=128, MR=1 -> BM=64 (skinny-N/K).
// Kloop = K iterations, lda = row stride of A and Wt (differ for split-K).
// modes: 1 = relu fp32   2 = relu bf16   5 = fused QKV fragment-major
//        6 = relu + fused pool (atomicAdd)
//        7 = split-K partial: blockIdx.z selects K-half; raw bf16 store
// ---------------------------------------------------------------------------
template <int MR>
__global__ __launch_bounds__(256) void gemm_mfma(
    const ushort* __restrict__ Asrc, const ushort* __restrict__ Wt,
    const float* __restrict__ bias, const float* __restrict__ biasK,
    const float* __restrict__ biasV, void* __restrict__ outp,
    int Kloop, int lda, int ldc, int mode)
{
    constexpr int BM = MR * 64;
    __shared__ ushort sA[BM * 72];
    __shared__ ushort sB[128 * 72];

    const int tid = threadIdx.x;
    const int wid = tid >> 6, lane = tid & 63;
    const int c = lane & 31, g = lane >> 5;
    const int wr = wid >> 1, wc = wid & 1;
    const int m0 = blockIdx.x * BM;
    const int n0 = blockIdx.y * 128;

    size_t zout = 0;
    if (mode == 7) {
        const int h = blockIdx.z;
        Asrc += (size_t)h * Kloop;
        Wt   += (size_t)h * Kloop;
        zout  = (size_t)h * M_ * A_;
    }

    f32x16 acc[MR][2] = {};

    for (int k0 = 0; k0 < Kloop; k0 += 64) {
        __syncthreads();
#pragma unroll
        for (int it = 0; it < BM / 32; ++it) {
            int idx = it * 256 + tid, r = idx >> 3, cc = (idx & 7) * 8;
            *(uint4*)&sA[r * 72 + cc] =
                *(const uint4*)(Asrc + (size_t)(m0 + r) * lda + k0 + cc);
        }
#pragma unroll
        for (int it = 0; it < 4; ++it) {
            int idx = it * 256 + tid, r = idx >> 3, cc = (idx & 7) * 8;
            *(uint4*)&sB[r * 72 + cc] =
                *(const uint4*)(Wt + (size_t)(n0 + r) * lda + k0 + cc);
        }
        __syncthreads();
#pragma unroll
        for (int ks = 0; ks < 4; ++ks) {
            const int ko = ks * 16 + 8 * g;
            short8 b0 = *(const short8*)&sB[(wc * 64 + c) * 72 + ko];
            short8 b1 = *(const short8*)&sB[(wc * 64 + 32 + c) * 72 + ko];
#pragma unroll
            for (int mr = 0; mr < MR; ++mr) {
                short8 a = *(const short8*)&sA[((wr * MR + mr) * 32 + c) * 72 + ko];
                acc[mr][0] = MFMA32(a, b0, acc[mr][0]);
                acc[mr][1] = MFMA32(a, b1, acc[mr][1]);
            }
        }
    }

    const int sec = n0 >> 8;  // for mode 5 (block-uniform)
    const float* bp = bias;
    int nw = n0;
    if (mode == 5) {
        bp = (sec == 0 ? bias : sec == 1 ? biasK : biasV);
        nw = n0 & 255;
    }
    const float bz[2] = { bp[nw + wc * 64 + c], bp[nw + wc * 64 + 32 + c] };

    float colsum[2] = { 0.f, 0.f };

#pragma unroll
    for (int mr = 0; mr < MR; ++mr) {
#pragma unroll
        for (int ct = 0; ct < 2; ++ct) {
            const int colbase = n0 + wc * 64 + ct * 32 + c;
            const float addb = (mode == 7) ? 0.f : bz[ct];
#pragma unroll
            for (int rg = 0; rg < 4; ++rg) {
                const int row = m0 + (wr * MR + mr) * 32 + 8 * rg + 4 * g;
                float v0 = acc[mr][ct][4 * rg + 0] + addb;
                float v1 = acc[mr][ct][4 * rg + 1] + addb;
                float v2 = acc[mr][ct][4 * rg + 2] + addb;
                float v3 = acc[mr][ct][4 * rg + 3] + addb;
                if (mode == 1 || mode == 2 || mode == 6) {
                    v0 = fmaxf(v0, 0.f); v1 = fmaxf(v1, 0.f);
                    v2 = fmaxf(v2, 0.f); v3 = fmaxf(v3, 0.f);
                }
                if (mode == 1) {
                    float* o = (float*)outp;
                    o[(size_t)(row + 0) * ldc + colbase] = v0;
                    o[(size_t)(row + 1) * ldc + colbase] = v1;
                    o[(size_t)(row + 2) * ldc + colbase] = v2;
                    o[(size_t)(row + 3) * ldc + colbase] = v3;
                } else if (mode == 2 || mode == 7) {
                    ushort* o = (ushort*)outp + zout;
                    o[(size_t)(row + 0) * ldc + colbase] = (ushort)f2b1(v0);
                    o[(size_t)(row + 1) * ldc + colbase] = (ushort)f2b1(v1);
                    o[(size_t)(row + 2) * ldc + colbase] = (ushort)f2b1(v2);
                    o[(size_t)(row + 3) * ldc + colbase] = (ushort)f2b1(v3);
                } else if (mode == 6) {
                    colsum[ct] += v0 + v1 + v2 + v3;
                } else {  // mode 5, fragment-major
                    const int cw = colbase & 255;
                    const int hh = cw >> 7, dd = cw & (D_ - 1);
                    if (sec < 2) {
                        ushort* o = (ushort*)outp + (size_t)sec * QKV_E;
#pragma unroll
                        for (int r2 = 0; r2 < 4; ++r2) {
                            int rw = row + r2;
                            int bb = rw >> 10, np = rw & (N_ - 1);
                            float vv = (r2 == 0 ? v0 : r2 == 1 ? v1 : r2 == 2 ? v2 : v3);
                            size_t off = (((size_t)(bb * H_ + hh) * 32 + (np >> 5)) * 16
                                          + (dd >> 3)) * 256
                                         + (np & 31) * 8 + (dd & 7);
                            o[off] = (ushort)f2b1(vv);
                        }
                    } else {
                        ushort* o = (ushort*)outp + 2 * QKV_E;
                        const int bb = row >> 10, np = row & (N_ - 1);
                        size_t off = ((((size_t)(bb * H_ + hh) * 32 + (np >> 5)) * 4
                                       + (dd >> 5)) * 4 + ((np & 31) >> 3)) * 256
                                     + (dd & 31) * 8 + (np & 7);
                        uint2 w = { f2b2(v0, v1), f2b2(v2, v3) };
                        *(uint2*)(o + off) = w;
                    }
                }
            }
        }
    }

    if (mode == 6) {
        float* part = (float*)outp;
        const int b = m0 >> 10;   // BM=64 divides 1024
#pragma unroll
        for (int ct = 0; ct < 2; ++ct) {
            float cs = colsum[ct] + __shfl_xor(colsum[ct], 32, 64);
            if (g == 0)
                atomicAdd(&part[(size_t)b * A_ + n0 + wc * 64 + ct * 32 + c], cs);
        }
    }
}

// ---------------------------------------------------------------------------
// Flash attention, barrier-free, fragment-major operands (R14-proven body).
// SPLIT=2: measured optimum of the split-KV trade (R18/R20 = ~336µs; SPLIT=1
// and SPLIT=4 both worse). 1024 blocks keep ~2 resident waves/SIMD.
// ---------------------------------------------------------------------------
#define OPITCH 132   // epilogue overlay pitch (66 words: bank-stride 2, free)

__global__ __launch_bounds__(128, 2) void attn_kernel(
    const ushort* __restrict__ qg, const ushort* __restrict__ kg,
    const ushort* __restrict__ vtg, ushort* __restrict__ po,
    float* __restrict__ pm, float* __restrict__ pl)
{
    __shared__ ushort sO[64 * OPITCH];   // 16896 B, epilogue only

    const int tid = threadIdx.x;
    const int w = tid >> 6, lane = tid & 63;
    const int c = lane & 31, g = lane >> 5;

    // XCD-aware decomposition: 64 (z,bh) pairs -> 8 per XCD; 16 q-tiles share
    // one pair's 256KB K/V working set in that XCD's L2.
    const int flat = blockIdx.x;          // 0..1023
    const int xcd  = flat & 7;
    const int ii   = flat >> 3;           // 0..127
    const int pair = xcd * 8 + (ii & 7);  // 0..63 = (z,bh)
    const int qt   = ii >> 3;             // 0..15
    const int bh   = pair & 31;
    const int z    = pair >> 5;           // 0..1

    const int q0 = qt * 64 + w * 32;
    const float scale2 = 0.08838834764831845f * 1.44269504f;  // /sqrt(128)*log2e
    const float THR = 11.5f;
    const int lo8 = c * 8;

    short8 qf[8];
    const ushort* qt_ = qg + ((size_t)bh * 32 + (q0 >> 5)) * 4096;
#pragma unroll
    for (int ks = 0; ks < 8; ++ks)
        qf[ks] = *(const short8*)(qt_ + (2 * ks + g) * 256 + lo8);

    f32x16 oacc[4] = {};
    float m = -1e30f, l = 0.f;

    // K prefetch for tile 0 (named regs; rule #20: no arrays)
    const size_t chunk0 = ((size_t)bh * 32 + z * TPC) * 4096;
    const ushort* kb0 = kg + chunk0 + g * 256 + lo8;
    short8 kf0 = *(const short8*)(kb0 + 0 * 512);
    short8 kf1 = *(const short8*)(kb0 + 1 * 512);
    short8 kf2 = *(const short8*)(kb0 + 2 * 512);
    short8 kf3 = *(const short8*)(kb0 + 3 * 512);
    short8 kf4 = *(const short8*)(kb0 + 4 * 512);
    short8 kf5 = *(const short8*)(kb0 + 5 * 512);
    short8 kf6 = *(const short8*)(kb0 + 6 * 512);
    short8 kf7 = *(const short8*)(kb0 + 7 * 512);

    for (int t = 0; t < TPC; ++t) {
        const size_t tb = chunk0 + (size_t)t * 4096;

        // ---- issue V(t) loads first: QK's MFMA chain below covers them ----
        const ushort* vb = vtg + tb + g * 256 + lo8;
        short8 vfA0 = *(const short8*)(vb + 0 * 1024);
        short8 vfA1 = *(const short8*)(vb + 1 * 1024);
        short8 vfA2 = *(const short8*)(vb + 2 * 1024);
        short8 vfA3 = *(const short8*)(vb + 3 * 1024);
        short8 vfB0 = *(const short8*)(vb + 0 * 1024 + 512);
        short8 vfB1 = *(const short8*)(vb + 1 * 1024 + 512);
        short8 vfB2 = *(const short8*)(vb + 2 * 1024 + 512);
        short8 vfB3 = *(const short8*)(vb + 3 * 1024 + 512);
        __builtin_amdgcn_sched_barrier(0);

        // ---- S^T = K · Q^T  (K already in registers) ----
        f32x16 sacc = {};
        __builtin_amdgcn_s_setprio(1);
        sacc = MFMA32(kf0, qf[0], sacc);
        sacc = MFMA32(kf1, qf[1], sacc);
        sacc = MFMA32(kf2, qf[2], sacc);
        sacc = MFMA32(kf3, qf[3], sacc);
        sacc = MFMA32(kf4, qf[4], sacc);
        sacc = MFMA32(kf5, qf[5], sacc);
        sacc = MFMA32(kf6, qf[6], sacc);
        sacc = MFMA32(kf7, qf[7], sacc);
        __builtin_amdgcn_s_setprio(0);

        // ---- prefetch K(t+1): lands during softmax+PV below ----
        if (t + 1 < TPC) {
            const ushort* kb2 = kg + tb + 4096 + g * 256 + lo8;
            kf0 = *(const short8*)(kb2 + 0 * 512);
            kf1 = *(const short8*)(kb2 + 1 * 512);
            kf2 = *(const short8*)(kb2 + 2 * 512);
            kf3 = *(const short8*)(kb2 + 3 * 512);
            kf4 = *(const short8*)(kb2 + 4 * 512);
            kf5 = *(const short8*)(kb2 + 5 * 512);
            kf6 = *(const short8*)(kb2 + 6 * 512);
            kf7 = *(const short8*)(kb2 + 7 * 512);
        }
        __builtin_amdgcn_sched_barrier(0);

        // ---- online softmax (exp2 domain, defer-max) ----
        float p[16];
        float tmax = -1e30f;
#pragma unroll
        for (int r = 0; r < 16; ++r) {
            float s = sacc[r] * scale2;
            p[r] = s;
            tmax = fmaxf(tmax, s);
        }
        tmax = fmaxf(tmax, __shfl_xor(tmax, 32, 64));
        if (!__all(tmax - m <= THR)) {
            const float mnew = fmaxf(m, tmax);
            const float corr = exp2f(m - mnew);
#pragma unroll
            for (int dt = 0; dt < 4; ++dt)
#pragma unroll
                for (int r = 0; r < 16; ++r) oacc[dt][r] *= corr;
            l *= corr;
            m = mnew;
        }
        float tsum = 0.f;
#pragma unroll
        for (int r = 0; r < 16; ++r) {
            p[r] = exp2f(p[r] - m);
            tsum += p[r];
        }
        tsum += __shfl_xor(tsum, 32, 64);
        l += tsum;

        uint pk[8];
#pragma unroll
        for (int pp = 0; pp < 8; ++pp)
            pk[pp] = f2b2(p[2 * pp], p[2 * pp + 1]);

        uint v0 = g ? pk[0] : pk[2];
        uint v1 = g ? pk[1] : pk[3];
        uint v2 = g ? pk[4] : pk[6];
        uint v3 = g ? pk[5] : pk[7];
        uint r0 = (uint)__shfl_xor((int)v0, 32, 64);
        uint r1 = (uint)__shfl_xor((int)v1, 32, 64);
        uint r2 = (uint)__shfl_xor((int)v2, 32, 64);
        uint r3 = (uint)__shfl_xor((int)v3, 32, 64);

        // ---- O^T += V^T · P^T  (V already in registers) ----
        __builtin_amdgcn_s_setprio(1);
#pragma unroll
        for (int kb = 0; kb < 2; ++kb) {
            union { uint u[4]; short8 s; } pf;
            if (kb == 0) {
                pf.u[0] = g ? r0 : pk[0];
                pf.u[1] = g ? r1 : pk[1];
                pf.u[2] = g ? pk[2] : r0;
                pf.u[3] = g ? pk[3] : r1;
            } else {
                pf.u[0] = g ? r2 : pk[4];
                pf.u[1] = g ? r3 : pk[5];
                pf.u[2] = g ? pk[6] : r2;
                pf.u[3] = g ? pk[7] : r3;
            }
            oacc[0] = MFMA32(kb ? vfB0 : vfA0, pf.s, oacc[0]);
            oacc[1] = MFMA32(kb ? vfB1 : vfA1, pf.s, oacc[1]);
            oacc[2] = MFMA32(kb ? vfB2 : vfA2, pf.s, oacc[2]);
            oacc[3] = MFMA32(kb ? vfB3 : vfA3, pf.s, oacc[3]);
        }
        __builtin_amdgcn_s_setprio(0);
    }

    if (lane < 32) {
        pm[(size_t)(z * 32 + bh) * N_ + q0 + c] = m;
        pl[(size_t)(z * 32 + bh) * N_ + q0 + c] = l;
    }
    {
        const int qrl = w * 32 + c;
#pragma unroll
        for (int dt = 0; dt < 4; ++dt)
#pragma unroll
            for (int rg = 0; rg < 4; ++rg) {
                int d = dt * 32 + 8 * rg + 4 * g;
                uint2 pv = { f2b2(oacc[dt][4 * rg + 0], oacc[dt][4 * rg + 1]),
                             f2b2(oacc[dt][4 * rg + 2], oacc[dt][4 * rg + 3]) };
                *(uint2*)&sO[qrl * OPITCH + d] = pv;
            }
    }
    __syncthreads();
    {
        const size_t pbase = ((size_t)(z * 32 + bh) * N_ + qt * 64) * D_;
#pragma unroll
        for (int it = 0; it < 16; ++it) {
            int idx = it * 128 + tid;
            int r = idx >> 5, dgr = (idx & 31) * 4;
            uint2 v = *(const uint2*)&sO[r * OPITCH + dgr];
            *(uint2*)(po + pbase + (size_t)r * D_ + dgr) = v;
        }
    }
}

// ---------------------------------------------------------------------------
// Combine split-KV partials -> bf16 [b][n][A], 8 elems/thread (vectorized)
// ---------------------------------------------------------------------------
__global__ __launch_bounds__(256) void combine_kernel(
    const ushort* __restrict__ po, const float* __restrict__ pm,
    const float* __restrict__ pl, ushort* __restrict__ out)
{
    const int idx = blockIdx.x * 256 + threadIdx.x;   // 524288 granules
    const int row = idx >> 4, d0 = (idx & 15) * 8;
    const int R = B_ * H_ * N_;  // 32768

    float ms[SPLIT];
    float M = -1e30f;
#pragma unroll
    for (int s = 0; s < SPLIT; ++s) {
        ms[s] = pm[(size_t)s * R + row];
        M = fmaxf(M, ms[s]);
    }
    float L = 0.f;
    float acc[8] = {};
#pragma unroll
    for (int s = 0; s < SPLIT; ++s) {
        float wgt = exp2f(ms[s] - M);
        L += pl[(size_t)s * R + row] * wgt;
        uint4 pv = *(const uint4*)(po + ((size_t)s * R + row) * D_ + d0);
        const ushort* pu = (const ushort*)&pv;
#pragma unroll
        for (int j = 0; j < 8; ++j) acc[j] += b2f(pu[j]) * wgt;
    }
    const float inv = 1.f / L;
    uint4 w;
    w.x = f2b2(acc[0] * inv, acc[1] * inv);
    w.y = f2b2(acc[2] * inv, acc[3] * inv);
    w.z = f2b2(acc[4] * inv, acc[5] * inv);
    w.w = f2b2(acc[6] * inv, acc[7] * inv);
    const int bh = row >> 10, n = row & (N_ - 1);
    const int bb = bh >> 1, hh = bh & 1;
    *(uint4*)(out + ((size_t)(bb * N_ + n)) * A_ + hh * D_ + d0) = w;
}

// ---------------------------------------------------------------------------
// add+LN with split-K join:
//   roll = relu(r0 + r1 + b2); stepb <- LN(roll + stepb)*g + b   (in place)
// ---------------------------------------------------------------------------
__global__ __launch_bounds__(256) void add_ln_kernel(
    const ushort* __restrict__ roll0, const ushort* __restrict__ roll1,
    const float* __restrict__ b2, ushort* __restrict__ stepb,
    const float* __restrict__ g, const float* __restrict__ bta)
{
    const int row = blockIdx.x * 4 + (threadIdx.x >> 6);
    const int lane = threadIdx.x & 63, c4 = lane * 4;
    const size_t base = (size_t)row * A_ + c4;

    uint2 ra = *(const uint2*)(roll0 + base);
    uint2 rb = *(const uint2*)(roll1 + base);
    uint2 pb = *(const uint2*)(stepb + base);
    float4 bz = *(const float4*)(b2 + c4);

    float r0 = fmaxf(b2f((ushort)(ra.x & 0xffff)) + b2f((ushort)(rb.x & 0xffff)) + bz.x, 0.f);
    float r1 = fmaxf(b2f((ushort)(ra.x >> 16))    + b2f((ushort)(rb.x >> 16))    + bz.y, 0.f);
    float r2 = fmaxf(b2f((ushort)(ra.y & 0xffff)) + b2f((ushort)(rb.y & 0xffff)) + bz.z, 0.f);
    float r3 = fmaxf(b2f((ushort)(ra.y >> 16))    + b2f((ushort)(rb.y >> 16))    + bz.w, 0.f);

    float v0 = r0 + b2f((ushort)(pb.x & 0xffff));
    float v1 = r1 + b2f((ushort)(pb.x >> 16));
    float v2 = r2 + b2f((ushort)(pb.y & 0xffff));
    float v3 = r3 + b2f((ushort)(pb.y >> 16));

    float s  = v0 + v1 + v2 + v3;
    float s2 = v0 * v0 + v1 * v1 + v2 * v2 + v3 * v3;
#pragma unroll
    for (int o = 32; o > 0; o >>= 1) {
        s  += __shfl_xor(s, o, 64);
        s2 += __shfl_xor(s2, o, 64);
    }
    const float mu = s * (1.f / A_);
    const float rs = rsqrtf(s2 * (1.f / A_) - mu * mu + EPS_);

    float4 gv = *(const float4*)(g + c4);
    float4 bv = *(const float4*)(bta + c4);
    float y0 = (v0 - mu) * rs * gv.x + bv.x;
    float y1 = (v1 - mu) * rs * gv.y + bv.y;
    float y2 = (v2 - mu) * rs * gv.z + bv.z;
    float y3 = (v3 - mu) * rs * gv.w + bv.w;

    uint2 yb = { f2b2(y0, y1), f2b2(y2, y3) };
    *(uint2*)(stepb + base) = yb;
}

// ---------------------------------------------------------------------------
// Final: pooled = part/N -> relu(pooled @ We + be)
// ---------------------------------------------------------------------------
__global__ __launch_bounds__(256) void final_kernel(
    const float* __restrict__ part, const float* __restrict__ We,
    const float* __restrict__ be, float* __restrict__ out)
{
    __shared__ float sp[A_];
    const int b = blockIdx.x, tid = threadIdx.x;
    sp[tid] = part[(size_t)b * A_ + tid] * (1.0f / N_);
    __syncthreads();
    float acc = be[tid];
    for (int kk = 0; kk < A_; ++kk) acc += sp[kk] * We[(size_t)kk * A_ + tid];
    out[b * A_ + tid] = fmaxf(acc, 0.f);
}

// ---------------------------------------------------------------------------
extern "C" void kernel_launch(void* const* d_in, const int* in_sizes, int n_in,
                              void* d_out, int out_size, void* d_ws, size_t ws_size,
                              hipStream_t stream)
{
    const float* X    = (const float*)d_in[0];
    const float* Wq   = (const float*)d_in[1];
    const float* bq   = (const float*)d_in[2];
    const float* Wk   = (const float*)d_in[3];
    const float* bk   = (const float*)d_in[4];
    const float* Wv   = (const float*)d_in[5];
    const float* bv   = (const float*)d_in[6];
    const float* W1   = (const float*)d_in[7];
    const float* b1   = (const float*)d_in[8];
    const float* W2   = (const float*)d_in[9];
    const float* b2   = (const float*)d_in[10];
    const float* ln_g = (const float*)d_in[11];
    const float* ln_b = (const float*)d_in[12];
    const float* Wc   = (const float*)d_in[13];
    const float* bc   = (const float*)d_in[14];
    const float* We   = (const float*)d_in[15];
    const float* be   = (const float*)d_in[16];

    // ---- workspace layout ----
    char* base = (char*)d_ws;
    ushort* qb     = (ushort*)base;  base += QKV_E * 2;   // q; attnb alias
    /* kb */                         base += QKV_E * 2;
    /* vt */                         base += QKV_E * 2;
    ushort* hbuf   = (ushort*)base;  base += (size_t)M_ * FFN_ * 2;  // aliases po
    ushort* rollp  = (ushort*)base;  base += (size_t)2 * M_ * A_ * 2; // split-K halves
    ushort* stepb  = (ushort*)base;  base += (size_t)M_ * A_ * 2;    // bf16 residual
    ushort* wqkv_t = (ushort*)base;  base += (size_t)3 * 3 * A_ * A_ * 2;
    ushort* w1_t   = (ushort*)base;  base += (size_t)3 * A_ * FFN_ * 2;
    ushort* w2_t   = (ushort*)base;  base += (size_t)3 * FFN_ * A_ * 2;
    ushort* wc_t   = (ushort*)base;  base += (size_t)A_ * A_ * 2;
    float*  part   = (float*)base;   base += (size_t)B_ * A_ * 4;
    float*  pm     = (float*)base;   base += (size_t)SPLIT * B_ * H_ * N_ * 4;
    float*  pl     = (float*)base;   base += (size_t)SPLIT * B_ * H_ * N_ * 4;
    ushort* kbuf   = qb + QKV_E;
    ushort* vtbuf  = qb + 2 * QKV_E;
    ushort* po     = hbuf;           // partial O: dead before FFN1 writes hbuf
    ushort* attnb  = qb;             // combine out: q dead after attn_kernel

    // ---- weight/input prep (2 launches) ----
    prep_kernel<<<dim3(32, 8, 16), 256, 0, stream>>>(
        Wq, Wk, Wv, W1, W2, Wc, wqkv_t, w1_t, w2_t, wc_t);
    f32_to_bf16_kernel<<<(M_ * A_) / (256 * 8), 256, 0, stream>>>(X, stepb);

    for (int i = 0; i < 3; ++i) {
        gemm_mfma<2><<<dim3(M_/128, 6), 256, 0, stream>>>(
            stepb, wqkv_t + (size_t)i * 3 * A_ * A_,
            bq + i * A_, bk + i * A_, bv + i * A_, qb, A_, A_, 0, 5);

        attn_kernel<<<16 * SPLIT * B_ * H_, 128, 0, stream>>>(
            qb, kbuf, vtbuf, po, pm, pl);
        combine_kernel<<<(B_*H_*N_*D_)/(256*8), 256, 0, stream>>>(po, pm, pl, attnb);

        gemm_mfma<2><<<dim3(M_/128, FFN_/128), 256, 0, stream>>>(
            attnb, w1_t + (size_t)i * A_ * FFN_, b1 + i * FFN_, nullptr, nullptr,
            hbuf, A_, A_, FFN_, 2);
        gemm_mfma<1><<<dim3(M_/64, A_/128, 2), 256, 0, stream>>>(
            hbuf, w2_t + (size_t)i * FFN_ * A_, b2 + i * A_, nullptr, nullptr,
            rollp, FFN_/2, FFN_, A_, 7);

        add_ln_kernel<<<M_/4, 256, 0, stream>>>(
            rollp, rollp + (size_t)M_ * A_, b2 + i * A_, stepb, ln_g, ln_b);
    }

    // head: fused relu+pool via atomics into part (zeroed per call)
    hipMemsetAsync(part, 0, (size_t)B_ * A_ * 4, stream);
    gemm_mfma<1><<<dim3(M_/64, A_/128), 256, 0, stream>>>(
        stepb, wc_t, bc, nullptr, nullptr, part, A_, A_, 0, 6);
    final_kernel<<<B_, 256, 0, stream>>>(part, We, be, (float*)d_out);
}